// Round 2
// baseline (322.852 us; speedup 1.0000x reference)
//
#include <hip/hip_runtime.h>
#include <hip/hip_bf16.h>
#include <cstdint>

typedef __attribute__((ext_vector_type(8))) short v8s;   // 8 x bf16 (4 VGPR) MFMA frag
typedef __attribute__((ext_vector_type(4))) float v4f;   // MFMA accum

__device__ __forceinline__ unsigned short f32_to_bf16(float f) {
  unsigned int u = __builtin_bit_cast(unsigned int, f);
  u += 0x7fffu + ((u >> 16) & 1u);           // RNE
  return (unsigned short)(u >> 16);
}

__device__ __forceinline__ void gload_lds16(const void* g, void* l) {
  __builtin_amdgcn_global_load_lds((const __attribute__((address_space(1))) void*)g,
                                   (__attribute__((address_space(3))) void*)l, 16, 0, 0);
}

// ---------------------------------------------------------------------------
// 256x256x(BK=64) 8-phase NT GEMM: C[M,N] = A[M,K] * B[N,K]^T (+ epilogue).
// 512 thr = 8 waves (2M x 4N), 128x64 output per wave, mfma_f32_16x16x32_bf16.
// LDS 128 KiB: smA/smB[2 dbuf][2 half][128][64], XOR-swizzled via pre-swizzled
// global source (validated conflict-free in round 1).
// Schedule per iter (2 K-tiles, phases 0-7, tiles 2i->buf0, 2i+1->buf1):
//   ph0 buf0 fmh0 kk0 +B | stage SB1(2i+1)    ph4 buf1 fmh0 kk0 +B | SB1(2i+2)
//   ph1 buf0 fmh0 kk1 +B | stage SA1(2i+1)    ph5 buf1 fmh0 kk1 +B | SA1(2i+2)
//   ph2 buf0 fmh1 kk0    | stage SA0(2i+2)    ph6 buf1 fmh1 kk0    | SA0(2i+3)
//   ph3 buf0 fmh1 kk1    | SB0(2i+2) vmcnt(4) ph7 buf1 fmh1 kk1    | SB0(2i+3) vmcnt(4)
// Issue-after-last-read and landing-before-first-read both verified per region.
// ---------------------------------------------------------------------------
enum { EPI_BF16_BIAS = 0, EPI_F32_BIAS = 1, EPI_F32_SCALE_ADD = 2 };

#define SG_A(bufi, half, rowoff, tau) \
  gload_lds16(Ag + (long long)((half)*128 + (rowoff) + rS) * lda + (long long)(tau)*64 + swz, \
              &smA[bufi][half][(rowoff) + wb][0])
#define SG_B(bufi, half, rowoff, tau) \
  gload_lds16(Bg + (long long)((half)*128 + (rowoff) + rS) * ldb + (long long)(tau)*64 + swz, \
              &smB[bufi][half][(rowoff) + wb][0])

#define PHASE(bufi, fmh, kk, READB, STAGES, TAILS) \
  { \
    v8s afr[4]; \
    _Pragma("unroll") \
    for (int j = 0; j < 4; ++j) { \
      const int r = ((fmh)*4 + j)*16 + l15; \
      afr[j] = *(const v8s*)&smA[bufi][wm][r][(((kk)*4 + l4) ^ (r & 7)) * 8]; \
    } \
    if (READB) { \
      _Pragma("unroll") \
      for (int j = 0; j < 4; ++j) { \
        const int r = wn64 + j*16 + l15; \
        bfr[kk][j] = *(const v8s*)&smB[bufi][wnh][r][(((kk)*4 + l4) ^ (r & 7)) * 8]; \
      } \
    } \
    STAGES \
    __builtin_amdgcn_s_barrier(); \
    asm volatile("s_waitcnt lgkmcnt(0)" ::: "memory"); \
    __builtin_amdgcn_s_setprio(1); \
    _Pragma("unroll") \
    for (int j = 0; j < 4; ++j) { \
      _Pragma("unroll") \
      for (int fn = 0; fn < 4; ++fn) \
        acc[(fmh)*4 + j][fn] = __builtin_amdgcn_mfma_f32_16x16x32_bf16( \
            afr[j], bfr[kk][fn], acc[(fmh)*4 + j][fn], 0, 0, 0); \
    } \
    __builtin_amdgcn_s_setprio(0); \
    TAILS \
    __builtin_amdgcn_s_barrier(); \
  }

template <int MODE>
__global__ __launch_bounds__(512, 2)
void gemm256(const unsigned short* __restrict__ A, long long strideA, int lda,
             const unsigned short* __restrict__ B, long long strideB, int ldb,
             void* __restrict__ Cout, long long strideC, int ldc,
             const float* __restrict__ bias,
             const float* __restrict__ addmat, long long strideAdd,
             float scale, int K)
{
  __shared__ __attribute__((aligned(16))) short smA[2][2][128][64];  // 64 KiB
  __shared__ __attribute__((aligned(16))) short smB[2][2][128][64];  // 64 KiB

  const int tid  = threadIdx.x;
  const int lane = tid & 63;
  const int wave = tid >> 6;          // 0..7
  const int wm   = wave >> 2;         // 0..1  (A half / M offset)
  const int wn   = wave & 3;          // 0..3  (N offset)
  const int wnh  = wn >> 1;           // B half
  const int wn64 = (wn & 1) * 64;     // row base within B half
  const int l15  = lane & 15, l4 = lane >> 4;
  const int bz   = blockIdx.z;
  const long long tileM = (long long)blockIdx.y * 256;
  const long long tileN = (long long)blockIdx.x * 256;

  const unsigned short* Ag = A + (long long)bz * strideA + tileM * lda;
  const unsigned short* Bg = B + (long long)bz * strideB + tileN * ldb;

  const int rS  = tid >> 3;                             // staging row 0..63
  const int swz = ((tid & 7) ^ ((tid >> 3) & 7)) * 8;   // pre-swizzled src col
  const int wb  = wave * 8;                             // wave LDS row base

  v4f acc[8][4] = {};
  v8s bfr[2][4];

  const int nt    = K >> 6;    // 64-wide K tiles (even)
  const int niter = nt >> 1;

  // ---- prologue: tile0 fully, tile1 SA0+SB0 (12 loads) ----
  SG_A(0, 0, 0, 0);  SG_A(0, 1, 0, 0);     // SA0(t0)
  SG_A(0, 0, 64, 0); SG_A(0, 1, 64, 0);    // SA1(t0)
  SG_B(0, 0, 0, 0);  SG_B(0, 0, 64, 0);    // SB0(t0)
  SG_B(0, 1, 0, 0);  SG_B(0, 1, 64, 0);    // SB1(t0)
  SG_A(1, 0, 0, 1);  SG_A(1, 1, 0, 1);     // SA0(t1)
  SG_B(1, 0, 0, 1);  SG_B(1, 0, 64, 1);    // SB0(t1)
  asm volatile("s_waitcnt vmcnt(4)" ::: "memory");
  __builtin_amdgcn_s_barrier();

  for (int i = 0; i < niter; ++i) {
    const int t1 = 2 * i + 1, t2 = 2 * i + 2, t3 = 2 * i + 3;
    const bool more = (i + 1 < niter);

    PHASE(0, 0, 0, 1, { SG_B(1, 1, 0, t1); SG_B(1, 1, 64, t1); }, {})
    PHASE(0, 0, 1, 1, { SG_A(1, 0, 64, t1); SG_A(1, 1, 64, t1); }, {})
    PHASE(0, 1, 0, 0, { if (more) { SG_A(0, 0, 0, t2); SG_A(0, 1, 0, t2); } }, {})
    PHASE(0, 1, 1, 0, { if (more) { SG_B(0, 0, 0, t2); SG_B(0, 0, 64, t2); } },
          { if (more) { asm volatile("s_waitcnt vmcnt(4)" ::: "memory"); }
            else      { asm volatile("s_waitcnt vmcnt(0)" ::: "memory"); } })
    PHASE(1, 0, 0, 1, { if (more) { SG_B(0, 1, 0, t2); SG_B(0, 1, 64, t2); } }, {})
    PHASE(1, 0, 1, 1, { if (more) { SG_A(0, 0, 64, t2); SG_A(0, 1, 64, t2); } }, {})
    PHASE(1, 1, 0, 0, { if (more) { SG_A(1, 0, 0, t3); SG_A(1, 1, 0, t3); } }, {})
    PHASE(1, 1, 1, 0, { if (more) { SG_B(1, 0, 0, t3); SG_B(1, 0, 64, t3); } },
          { if (more) { asm volatile("s_waitcnt vmcnt(4)" ::: "memory"); } })
  }

  // ---- epilogue: C/D layout col=lane&15, row=(lane>>4)*4+reg ----
  const int row0 = (int)tileM + wm * 128 + l4 * 4;
  const int col0 = (int)tileN + wn * 64 + l15;
  #pragma unroll
  for (int fm = 0; fm < 8; ++fm) {
    #pragma unroll
    for (int fn = 0; fn < 4; ++fn) {
      const int col = col0 + fn * 16;
      #pragma unroll
      for (int r = 0; r < 4; ++r) {
        const int row = row0 + fm * 16 + r;
        const float v = acc[fm][fn][r];
        if (MODE == EPI_F32_SCALE_ADD) {
          float* C = (float*)Cout + (long long)bz * strideC;
          const float* Wt = addmat + (long long)bz * strideAdd;
          C[(long long)row * ldc + col] = v * scale + Wt[(long long)row * ldc + col];
        } else if (MODE == EPI_F32_BIAS) {
          float* C = (float*)Cout + (long long)bz * strideC;
          C[(long long)row * ldc + col] = v + bias[col];
        } else {
          unsigned short* C = (unsigned short*)Cout + (long long)bz * strideC;
          const float b = bias ? bias[col] : 0.0f;
          C[(long long)row * ldc + col] = f32_to_bf16(v + b);
        }
      }
    }
  }
}

// ---------------------------------------------------------------------------
__global__ __launch_bounds__(256)
void cvt_f32_bf16_kernel(const float* __restrict__ in, unsigned short* __restrict__ out,
                         long long n)
{
  const long long i = ((long long)blockIdx.x * 256 + threadIdx.x) * 4;
  if (i >= n) return;
  const float4 v = *(const float4*)(in + i);
  typedef __attribute__((ext_vector_type(4))) unsigned short v4us;
  v4us o;
  o.x = f32_to_bf16(v.x); o.y = f32_to_bf16(v.y);
  o.z = f32_to_bf16(v.z); o.w = f32_to_bf16(v.w);
  *(v4us*)(out + i) = o;
}

__global__ __launch_bounds__(256)
void transpose_f32_bf16_kernel(const float* __restrict__ in, unsigned short* __restrict__ out,
                               int R, int C)   // in [R][C] f32 -> out [C][R] bf16
{
  __shared__ float t[32][33];
  const int c0 = blockIdx.x * 32, r0 = blockIdx.y * 32;
  const int tx = threadIdx.x, ty = threadIdx.y;
  for (int i = ty; i < 32; i += 8)
    t[i][tx] = in[(long long)(r0 + i) * C + (c0 + tx)];
  __syncthreads();
  for (int i = ty; i < 32; i += 8)
    out[(long long)(c0 + i) * R + (r0 + tx)] = f32_to_bf16(t[tx][i]);
}

__global__ __launch_bounds__(256)
void transpose_bf16_kernel(const unsigned short* __restrict__ in, long long strideIn, int ldin,
                           unsigned short* __restrict__ out, long long strideOut,
                           int R)   // per batch: in [R][*] (ld=ldin) -> out [C][R]
{
  __shared__ unsigned short t[32][33];
  const unsigned short* src = in + (long long)blockIdx.z * strideIn;
  unsigned short* dst = out + (long long)blockIdx.z * strideOut;
  const int c0 = blockIdx.x * 32, r0 = blockIdx.y * 32;
  const int tx = threadIdx.x, ty = threadIdx.y;
  for (int i = ty; i < 32; i += 8)
    t[i][tx] = src[(long long)(r0 + i) * ldin + (c0 + tx)];
  __syncthreads();
  for (int i = ty; i < 32; i += 8)
    dst[(long long)(c0 + i) * R + (r0 + tx)] = t[tx][i];
}

// one block (256 thr) per row of 2048 fp32 scores -> bf16 probs
__global__ __launch_bounds__(256)
void softmax_rows(const float* __restrict__ scores, unsigned short* __restrict__ probs)
{
  const long long row = blockIdx.x;
  const float* src = scores + row * 2048;
  unsigned short* dst = probs + row * 2048;
  const int t = threadIdx.x;
  float v[8];
  const float4 a = *(const float4*)(src + t * 8);
  const float4 b = *(const float4*)(src + t * 8 + 4);
  v[0]=a.x; v[1]=a.y; v[2]=a.z; v[3]=a.w; v[4]=b.x; v[5]=b.y; v[6]=b.z; v[7]=b.w;

  float m = v[0];
  #pragma unroll
  for (int j = 1; j < 8; ++j) m = fmaxf(m, v[j]);
  for (int o = 32; o; o >>= 1) m = fmaxf(m, __shfl_xor(m, o));
  __shared__ float redm[4], reds[4];
  if ((t & 63) == 0) redm[t >> 6] = m;
  __syncthreads();
  m = fmaxf(fmaxf(redm[0], redm[1]), fmaxf(redm[2], redm[3]));

  float s = 0.f;
  #pragma unroll
  for (int j = 0; j < 8; ++j) { v[j] = __expf(v[j] - m); s += v[j]; }
  for (int o = 32; o; o >>= 1) s += __shfl_xor(s, o);
  if ((t & 63) == 0) reds[t >> 6] = s;
  __syncthreads();
  s = reds[0] + reds[1] + reds[2] + reds[3];
  const float inv = 1.0f / s;

  v8s o8;
  #pragma unroll
  for (int j = 0; j < 8; ++j) o8[j] = (short)f32_to_bf16(v[j] * inv);
  *(v8s*)(dst + t * 8) = o8;
}

// ---------------------------------------------------------------------------
extern "C" void kernel_launch(void* const* d_in, const int* in_sizes, int n_in,
                              void* d_out, int out_size, void* d_ws, size_t ws_size,
                              hipStream_t stream) {
  (void)in_sizes; (void)n_in; (void)out_size; (void)ws_size;
  const float* x   = (const float*)d_in[0];
  const float* sw  = (const float*)d_in[1];
  const float* W_c = (const float*)d_in[2];
  const float* b_c = (const float*)d_in[3];
  const float* W_p = (const float*)d_in[4];
  const float* b_p = (const float*)d_in[5];
  float* out = (float*)d_out;

  const int Bb = 4, S = 2048, H = 1024, Ha = 1024, P = 1024;
  const int M = Bb * S;                              // 8192
  char* ws = (char*)d_ws;
  const long long MB = 1024LL * 1024LL;
  // ws layout (168 MB), time-sliced overlap in [0,64MB):
  //   x_bf [0,16) steps 1-4 | scores [0,64) steps 5-6 | ctx [0,16) steps 8-9
  float*          scores = (float*)(ws + 0);
  unsigned short* x_bf   = (unsigned short*)(ws + 0);
  unsigned short* ctx    = (unsigned short*)(ws + 0);
  unsigned short* probs  = (unsigned short*)(ws + 64 * MB);   // 32 MB
  unsigned short* qkv    = (unsigned short*)(ws + 96 * MB);   // 48 MB [8192][3072]
  unsigned short* Vt     = (unsigned short*)(ws + 144 * MB);  // 16 MB [4][1024][2048]
  unsigned short* Wc_t   = (unsigned short*)(ws + 160 * MB);  // 6 MB  [3072][1024]
  unsigned short* Wp_t   = (unsigned short*)(ws + 166 * MB);  // 2 MB  [1024][1024]

  const dim3 tb(32, 8);

  // 1) x -> bf16
  cvt_f32_bf16_kernel<<<(unsigned)((long long)M * H / 4 / 256), 256, 0, stream>>>(
      x, x_bf, (long long)M * H);
  // 2,3) W_c^T, W_p^T (f32 -> bf16)
  transpose_f32_bf16_kernel<<<dim3(3 * Ha / 32, H / 32), tb, 0, stream>>>(W_c, Wc_t, H, 3 * Ha);
  transpose_f32_bf16_kernel<<<dim3(P / 32, Ha / 32), tb, 0, stream>>>(W_p, Wp_t, Ha, P);
  // 4) qkv = x @ W_c + b_c   (bf16 out, ld 3072)
  gemm256<EPI_BF16_BIAS><<<dim3(3 * Ha / 256, M / 256, 1), 512, 0, stream>>>(
      x_bf, 0, H, Wc_t, 0, H, qkv, 0, 3 * Ha, b_c, nullptr, 0, 0.f, H);
  // 5) scores = (Q @ K^T) * rsqrt(1024) + score_weights   (fp32)
  gemm256<EPI_F32_SCALE_ADD><<<dim3(S / 256, S / 256, Bb), 512, 0, stream>>>(
      qkv, (long long)S * 3 * Ha, 3 * Ha,
      qkv + Ha, (long long)S * 3 * Ha, 3 * Ha,
      scores, (long long)S * S, S, nullptr, sw, (long long)S * S, 0.03125f, Ha);
  // 6) softmax -> bf16 probs
  softmax_rows<<<Bb * S, 256, 0, stream>>>(scores, probs);
  // 7) V^T per batch
  transpose_bf16_kernel<<<dim3(Ha / 32, S / 32, Bb), tb, 0, stream>>>(
      qkv + 2 * Ha, (long long)S * 3 * Ha, 3 * Ha, Vt, (long long)Ha * S, S);
  // 8) ctx = probs @ V   (bf16 out)
  gemm256<EPI_BF16_BIAS><<<dim3(Ha / 256, S / 256, Bb), 512, 0, stream>>>(
      probs, (long long)S * S, S, Vt, (long long)Ha * S, S,
      ctx, (long long)S * Ha, Ha, nullptr, nullptr, 0, 0.f, S);
  // 9) out = ctx @ W_p + b_p   (fp32 out)
  gemm256<EPI_F32_BIAS><<<dim3(P / 256, M / 256, 1), 512, 0, stream>>>(
      ctx, 0, Ha, Wp_t, 0, Ha, out, 0, P, b_p, nullptr, 0, 0.f, Ha);
}

// Round 4
// 297.725 us; speedup vs baseline: 1.0844x; 1.0844x over previous
//
#include <hip/hip_runtime.h>
#include <hip/hip_bf16.h>
#include <cstdint>

typedef __attribute__((ext_vector_type(8))) short v8s;   // 8 x bf16 (4 VGPR) MFMA frag
typedef __attribute__((ext_vector_type(4))) float v4f;   // MFMA accum

__device__ __forceinline__ unsigned short f32_to_bf16(float f) {
  unsigned int u = __builtin_bit_cast(unsigned int, f);
  u += 0x7fffu + ((u >> 16) & 1u);           // RNE
  return (unsigned short)(u >> 16);
}

__device__ __forceinline__ void gload_lds16(const void* g, void* l) {
  __builtin_amdgcn_global_load_lds((const __attribute__((address_space(1))) void*)g,
                                   (__attribute__((address_space(3))) void*)l, 16, 0, 0);
}

enum { EPI_BF16_BIAS = 0, EPI_F32_BIAS = 1, EPI_F32_SCALE_ADD = 2 };

// ---------------------------------------------------------------------------
// Round-1 proven 128x128 NT GEMM (used for PV and out-proj).
// ---------------------------------------------------------------------------
template <int MODE>
__global__ __launch_bounds__(256)
void gemm_nt(const unsigned short* __restrict__ A, long long strideA, int lda,
             const unsigned short* __restrict__ B, long long strideB, int ldb,
             void* __restrict__ Cout, long long strideC, int ldc,
             const float* __restrict__ bias,
             const float* __restrict__ addmat, long long strideAdd,
             float scale, int K)
{
  __shared__ __attribute__((aligned(16))) short smA[128 * 64];
  __shared__ __attribute__((aligned(16))) short smB[128 * 64];

  const int tid  = threadIdx.x;
  const int lane = tid & 63;
  const int wave = tid >> 6;
  const int wm = wave >> 1, wn = wave & 1;
  const int bz = blockIdx.z;
  const int tileM = blockIdx.y * 128, tileN = blockIdx.x * 128;

  const unsigned short* Ag = A + (long long)bz * strideA + (long long)tileM * lda;
  const unsigned short* Bg = B + (long long)bz * strideB + (long long)tileN * ldb;

  const int l8    = lane >> 3;
  const int srcCb = (lane & 7) ^ l8;

  v4f acc[4][4] = {};

  for (int k0 = 0; k0 < K; k0 += 64) {
    #pragma unroll
    for (int i = 0; i < 4; ++i) {
      const int c   = wave * 4 + i;
      const int row = c * 8 + l8;
      gload_lds16(Ag + (long long)row * lda + k0 + srcCb * 8, &smA[c * 512]);
      gload_lds16(Bg + (long long)row * ldb + k0 + srcCb * 8, &smB[c * 512]);
    }
    __syncthreads();
    #pragma unroll
    for (int kk = 0; kk < 2; ++kk) {
      v8s af[4], bf[4];
      #pragma unroll
      for (int f = 0; f < 4; ++f) {
        const int rA = wm * 64 + f * 16 + (lane & 15);
        const int cA = (kk * 4 + (lane >> 4)) ^ (rA & 7);
        af[f] = *(const v8s*)&smA[rA * 64 + cA * 8];
        const int rB = wn * 64 + f * 16 + (lane & 15);
        const int cB = (kk * 4 + (lane >> 4)) ^ (rB & 7);
        bf[f] = *(const v8s*)&smB[rB * 64 + cB * 8];
      }
      #pragma unroll
      for (int fm = 0; fm < 4; ++fm)
        #pragma unroll
        for (int fn = 0; fn < 4; ++fn)
          acc[fm][fn] = __builtin_amdgcn_mfma_f32_16x16x32_bf16(af[fm], bf[fn], acc[fm][fn], 0, 0, 0);
    }
    __syncthreads();
  }

  const int row0 = tileM + wm * 64 + (lane >> 4) * 4;
  const int col0 = tileN + wn * 64 + (lane & 15);
  #pragma unroll
  for (int fm = 0; fm < 4; ++fm) {
    #pragma unroll
    for (int fn = 0; fn < 4; ++fn) {
      const int col = col0 + fn * 16;
      #pragma unroll
      for (int r = 0; r < 4; ++r) {
        const int row = row0 + fm * 16 + r;
        const float v = acc[fm][fn][r];
        if (MODE == EPI_F32_SCALE_ADD) {
          float* C = (float*)Cout + (long long)bz * strideC;
          const float* Wt = addmat + (long long)bz * strideAdd;
          C[(long long)row * ldc + col] = v * scale + Wt[(long long)row * ldc + col];
        } else if (MODE == EPI_F32_BIAS) {
          float* C = (float*)Cout + (long long)bz * strideC;
          C[(long long)row * ldc + col] = v + bias[col];
        } else {
          unsigned short* C = (unsigned short*)Cout + (long long)bz * strideC;
          const float b = bias ? bias[col] : 0.0f;
          C[(long long)row * ldc + col] = f32_to_bf16(v + b);
        }
      }
    }
  }
}

// ---------------------------------------------------------------------------
// 256x256 8-phase NT GEMM v2 — derived-waits schedule.
// 512 thr = 8 waves (2M x 4N), 128x64 out/wave. Phases = (fmh, fnh) quadrants
// x full K=64. A-half(fmh) read ONLY in its 2 phases; B-strips(fnh) read ONLY
// in theirs -> region-safe staging with every vmcnt retiring loads issued
// >=3 phases earlier:
//   P0(0,0):st o.Ah1, vm6 | P1(0,1):st o.Bh1 | P2(1,0):st e'.Ah0 | P3(1,1):st e'.Bh0, vm8
//   P4(0,0):st e'.Ah1,vm6 | P5(0,1):st e'.Bh1| P6(1,0):st o'.Ah0 | P7(1,1):st o'.Bh0, vm8
// (e=2i->buf0, o=2i+1->buf1). Peeled final iteration: waits vm6@P0, vm4@P3, vm0@P4.
// Round-3 bug (fixed): l4 must be lane>>4 (K-block 0..3), NOT (lane>>4)*4 —
// col-block = (kk*4 + l4) ^ (row&7), range 0..7.
// ---------------------------------------------------------------------------

#define WAITVM(n) asm volatile("s_waitcnt vmcnt(" #n ")" ::: "memory")

#define STG_A(bufi, fmh, t) do { \
  gload_lds16(Ag + (long long)(gA0 + (fmh) * 64) * lda + (long long)(t) * 64 + swz, \
              &smA[bufi][hW][(fmh) * 64 + dA0][0]); \
  gload_lds16(Ag + (long long)(gA0 + 8 + (fmh) * 64) * lda + (long long)(t) * 64 + swz, \
              &smA[bufi][hW][(fmh) * 64 + dA0 + 8][0]); \
} while (0)

#define STG_B(bufi, fnh, t) do { \
  gload_lds16(Bg + (long long)(gB0 + (fnh) * 32) * ldb + (long long)(t) * 64 + swz, \
              &smB[bufi][hW][dB0 + (fnh) * 32][0]); \
  gload_lds16(Bg + (long long)(gB0 + 8 + (fnh) * 32) * ldb + (long long)(t) * 64 + swz, \
              &smB[bufi][hW][dB0 + (fnh) * 32 + 8][0]); \
} while (0)

#define PH(bufi, fmh, fnh, DOA, STAGE, TAIL) \
  { \
    if (DOA) { \
      _Pragma("unroll") \
      for (int j = 0; j < 4; ++j) { \
        afr[j][0] = *(const v8s*)&smA[bufi][wm][(fmh) * 64 + j * 16 + l15][((0 + l4) ^ l7) * 8]; \
        afr[j][1] = *(const v8s*)&smA[bufi][wm][(fmh) * 64 + j * 16 + l15][((4 + l4) ^ l7) * 8]; \
      } \
    } \
    v8s b00 = *(const v8s*)&smB[bufi][wnh][wn64 + ((fnh) * 2 + 0) * 16 + l15][((0 + l4) ^ l7) * 8]; \
    v8s b01 = *(const v8s*)&smB[bufi][wnh][wn64 + ((fnh) * 2 + 0) * 16 + l15][((4 + l4) ^ l7) * 8]; \
    v8s b10 = *(const v8s*)&smB[bufi][wnh][wn64 + ((fnh) * 2 + 1) * 16 + l15][((0 + l4) ^ l7) * 8]; \
    v8s b11 = *(const v8s*)&smB[bufi][wnh][wn64 + ((fnh) * 2 + 1) * 16 + l15][((4 + l4) ^ l7) * 8]; \
    STAGE; \
    __builtin_amdgcn_s_barrier(); \
    asm volatile("s_waitcnt lgkmcnt(0)" ::: "memory"); \
    __builtin_amdgcn_s_setprio(1); \
    _Pragma("unroll") \
    for (int j = 0; j < 4; ++j) { \
      acc[(fmh) * 4 + j][(fnh) * 2 + 0] = __builtin_amdgcn_mfma_f32_16x16x32_bf16(afr[j][0], b00, acc[(fmh) * 4 + j][(fnh) * 2 + 0], 0, 0, 0); \
      acc[(fmh) * 4 + j][(fnh) * 2 + 0] = __builtin_amdgcn_mfma_f32_16x16x32_bf16(afr[j][1], b01, acc[(fmh) * 4 + j][(fnh) * 2 + 0], 0, 0, 0); \
      acc[(fmh) * 4 + j][(fnh) * 2 + 1] = __builtin_amdgcn_mfma_f32_16x16x32_bf16(afr[j][0], b10, acc[(fmh) * 4 + j][(fnh) * 2 + 1], 0, 0, 0); \
      acc[(fmh) * 4 + j][(fnh) * 2 + 1] = __builtin_amdgcn_mfma_f32_16x16x32_bf16(afr[j][1], b11, acc[(fmh) * 4 + j][(fnh) * 2 + 1], 0, 0, 0); \
    } \
    __builtin_amdgcn_s_setprio(0); \
    TAIL; \
    __builtin_amdgcn_s_barrier(); \
  }

template <int MODE>
__global__ __launch_bounds__(512, 2)
void gemm256v2(const unsigned short* __restrict__ A, long long strideA, int lda,
               const unsigned short* __restrict__ B, long long strideB, int ldb,
               void* __restrict__ Cout, long long strideC, int ldc,
               const float* __restrict__ bias,
               const float* __restrict__ addmat, long long strideAdd,
               float scale, int K)
{
  __shared__ __attribute__((aligned(16))) short smA[2][2][128][64];  // 64 KiB
  __shared__ __attribute__((aligned(16))) short smB[2][2][128][64];  // 64 KiB

  const int tid  = threadIdx.x;
  const int lane = tid & 63;
  const int wave = tid >> 6;          // 0..7
  const int wm   = wave >> 2;         // A half for frag reads
  const int wn   = wave & 3;
  const int wnh  = wn >> 1;           // B half for frag reads
  const int wn64 = (wn & 1) * 64;
  const int l15  = lane & 15, l4 = lane >> 4, l7 = lane & 7;   // l4 FIXED
  const int bz   = blockIdx.z;
  const long long tileM = (long long)blockIdx.y * 256;
  const long long tileN = (long long)blockIdx.x * 256;

  const unsigned short* Ag = A + (long long)bz * strideA + tileM * lda;
  const unsigned short* Bg = B + (long long)bz * strideB + tileN * ldb;

  // staging geometry (per wave: 2 x 1KB chunks per half-tile call)
  const int hW  = wave >> 2;                          // LDS half (A and B)
  const int dA0 = (wave & 3) * 16;                    // A dest row base
  const int gA0 = hW * 128 + dA0 + (lane >> 3);       // A global row (lane-resolved)
  const int dB0 = ((wave >> 1) & 1) * 64 + (wave & 1) * 16;
  const int gB0 = hW * 128 + dB0 + (lane >> 3);
  const int swz = ((lane & 7) ^ ((lane >> 3) & 7)) * 8;

  v4f acc[8][4] = {};
  v8s afr[4][2];

  const int nt    = K >> 6;    // even, >= 4
  const int niter = nt >> 1;

  // ---- prologue: t0 fully, t1 {Ah0,Bh0}; order matters for vmcnt(8) ----
  STG_A(0, 0, 0); STG_B(0, 0, 0);   // t0.Ah0, t0.Bh0  (retired by the wait)
  STG_A(0, 1, 0); STG_B(0, 1, 0);   // t0.Ah1, t0.Bh1
  STG_A(1, 0, 1); STG_B(1, 0, 1);   // t1.Ah0, t1.Bh0
  WAITVM(8);
  __builtin_amdgcn_s_barrier();

  for (int i = 0; i < niter - 1; ++i) {
    const int o = 2 * i + 1, e2 = 2 * i + 2, o2 = 2 * i + 3;
    PH(0, 0, 0, 1, STG_A(1, 1, o),  WAITVM(6))
    PH(0, 0, 1, 0, STG_B(1, 1, o),  (void)0)
    PH(0, 1, 0, 1, STG_A(0, 0, e2), (void)0)
    PH(0, 1, 1, 0, STG_B(0, 0, e2), WAITVM(8))
    PH(1, 0, 0, 1, STG_A(0, 1, e2), WAITVM(6))
    PH(1, 0, 1, 0, STG_B(0, 1, e2), (void)0)
    PH(1, 1, 0, 1, STG_A(1, 0, o2), (void)0)
    PH(1, 1, 1, 0, STG_B(1, 0, o2), WAITVM(8))
  }
  // ---- peeled final iteration (no next-tile stages) ----
  {
    const int o = nt - 1;
    PH(0, 0, 0, 1, STG_A(1, 1, o), WAITVM(6))
    PH(0, 0, 1, 0, STG_B(1, 1, o), (void)0)
    PH(0, 1, 0, 1, (void)0,        (void)0)
    PH(0, 1, 1, 0, (void)0,        WAITVM(4))
    PH(1, 0, 0, 1, (void)0,        WAITVM(0))
    PH(1, 0, 1, 0, (void)0,        (void)0)
    PH(1, 1, 0, 1, (void)0,        (void)0)
    PH(1, 1, 1, 0, (void)0,        (void)0)
  }

  // ---- epilogue: C/D layout col=lane&15, row=(lane>>4)*4+reg ----
  const int row0 = (int)tileM + wm * 128 + (lane >> 4) * 4;
  const int col0 = (int)tileN + wn * 64 + l15;
  #pragma unroll
  for (int fm = 0; fm < 8; ++fm) {
    #pragma unroll
    for (int fn = 0; fn < 4; ++fn) {
      const int col = col0 + fn * 16;
      #pragma unroll
      for (int r = 0; r < 4; ++r) {
        const int row = row0 + fm * 16 + r;
        const float v = acc[fm][fn][r];
        if (MODE == EPI_F32_SCALE_ADD) {
          float* C = (float*)Cout + (long long)bz * strideC;
          const float* Wt = addmat + (long long)bz * strideAdd;
          C[(long long)row * ldc + col] = v * scale + Wt[(long long)row * ldc + col];
        } else if (MODE == EPI_F32_BIAS) {
          float* C = (float*)Cout + (long long)bz * strideC;
          C[(long long)row * ldc + col] = v + bias[col];
        } else {
          unsigned short* C = (unsigned short*)Cout + (long long)bz * strideC;
          const float b = bias ? bias[col] : 0.0f;
          C[(long long)row * ldc + col] = f32_to_bf16(v + b);
        }
      }
    }
  }
}

// ---------------------------------------------------------------------------
__global__ __launch_bounds__(256)
void cvt_f32_bf16_kernel(const float* __restrict__ in, unsigned short* __restrict__ out,
                         long long n)
{
  const long long i = ((long long)blockIdx.x * 256 + threadIdx.x) * 4;
  if (i >= n) return;
  const float4 v = *(const float4*)(in + i);
  typedef __attribute__((ext_vector_type(4))) unsigned short v4us;
  v4us o;
  o.x = f32_to_bf16(v.x); o.y = f32_to_bf16(v.y);
  o.z = f32_to_bf16(v.z); o.w = f32_to_bf16(v.w);
  *(v4us*)(out + i) = o;
}

__global__ __launch_bounds__(256)
void transpose_f32_bf16_kernel(const float* __restrict__ in, unsigned short* __restrict__ out,
                               int R, int C)   // in [R][C] f32 -> out [C][R] bf16
{
  __shared__ float t[32][33];
  const int c0 = blockIdx.x * 32, r0 = blockIdx.y * 32;
  const int tx = threadIdx.x, ty = threadIdx.y;
  for (int i = ty; i < 32; i += 8)
    t[i][tx] = in[(long long)(r0 + i) * C + (c0 + tx)];
  __syncthreads();
  for (int i = ty; i < 32; i += 8)
    out[(long long)(c0 + i) * R + (r0 + tx)] = f32_to_bf16(t[tx][i]);
}

__global__ __launch_bounds__(256)
void transpose_bf16_kernel(const unsigned short* __restrict__ in, long long strideIn, int ldin,
                           unsigned short* __restrict__ out, long long strideOut,
                           int R)
{
  __shared__ unsigned short t[32][33];
  const unsigned short* src = in + (long long)blockIdx.z * strideIn;
  unsigned short* dst = out + (long long)blockIdx.z * strideOut;
  const int c0 = blockIdx.x * 32, r0 = blockIdx.y * 32;
  const int tx = threadIdx.x, ty = threadIdx.y;
  for (int i = ty; i < 32; i += 8)
    t[i][tx] = src[(long long)(r0 + i) * ldin + (c0 + tx)];
  __syncthreads();
  for (int i = ty; i < 32; i += 8)
    dst[(long long)(c0 + i) * R + (r0 + tx)] = t[tx][i];
}

__global__ __launch_bounds__(256)
void softmax_rows(const float* __restrict__ scores, unsigned short* __restrict__ probs)
{
  const long long row = blockIdx.x;
  const float* src = scores + row * 2048;
  unsigned short* dst = probs + row * 2048;
  const int t = threadIdx.x;
  float v[8];
  const float4 a = *(const float4*)(src + t * 8);
  const float4 b = *(const float4*)(src + t * 8 + 4);
  v[0]=a.x; v[1]=a.y; v[2]=a.z; v[3]=a.w; v[4]=b.x; v[5]=b.y; v[6]=b.z; v[7]=b.w;

  float m = v[0];
  #pragma unroll
  for (int j = 1; j < 8; ++j) m = fmaxf(m, v[j]);
  for (int o = 32; o; o >>= 1) m = fmaxf(m, __shfl_xor(m, o));
  __shared__ float redm[4], reds[4];
  if ((t & 63) == 0) redm[t >> 6] = m;
  __syncthreads();
  m = fmaxf(fmaxf(redm[0], redm[1]), fmaxf(redm[2], redm[3]));

  float s = 0.f;
  #pragma unroll
  for (int j = 0; j < 8; ++j) { v[j] = __expf(v[j] - m); s += v[j]; }
  for (int o = 32; o; o >>= 1) s += __shfl_xor(s, o);
  if ((t & 63) == 0) reds[t >> 6] = s;
  __syncthreads();
  s = reds[0] + reds[1] + reds[2] + reds[3];
  const float inv = 1.0f / s;

  v8s o8;
  #pragma unroll
  for (int j = 0; j < 8; ++j) o8[j] = (short)f32_to_bf16(v[j] * inv);
  *(v8s*)(dst + t * 8) = o8;
}

// ---------------------------------------------------------------------------
extern "C" void kernel_launch(void* const* d_in, const int* in_sizes, int n_in,
                              void* d_out, int out_size, void* d_ws, size_t ws_size,
                              hipStream_t stream) {
  (void)in_sizes; (void)n_in; (void)out_size; (void)ws_size;
  const float* x   = (const float*)d_in[0];
  const float* sw  = (const float*)d_in[1];
  const float* W_c = (const float*)d_in[2];
  const float* b_c = (const float*)d_in[3];
  const float* W_p = (const float*)d_in[4];
  const float* b_p = (const float*)d_in[5];
  float* out = (float*)d_out;

  const int Bb = 4, S = 2048, H = 1024, Ha = 1024, P = 1024;
  const int M = Bb * S;                              // 8192
  char* ws = (char*)d_ws;
  const long long MB = 1024LL * 1024LL;
  // ws layout (168 MB), time-sliced overlap in [0,64MB):
  //   x_bf [0,16) steps 1-4 | scores [0,64) steps 5-6 | ctx [0,16) steps 8-9
  float*          scores = (float*)(ws + 0);
  unsigned short* x_bf   = (unsigned short*)(ws + 0);
  unsigned short* ctx    = (unsigned short*)(ws + 0);
  unsigned short* probs  = (unsigned short*)(ws + 64 * MB);   // 32 MB
  unsigned short* qkv    = (unsigned short*)(ws + 96 * MB);   // 48 MB [8192][3072]
  unsigned short* Vt     = (unsigned short*)(ws + 144 * MB);  // 16 MB [4][1024][2048]
  unsigned short* Wc_t   = (unsigned short*)(ws + 160 * MB);  // 6 MB  [3072][1024]
  unsigned short* Wp_t   = (unsigned short*)(ws + 166 * MB);  // 2 MB  [1024][1024]

  const dim3 tb(32, 8);

  // 1) x -> bf16
  cvt_f32_bf16_kernel<<<(unsigned)((long long)M * H / 4 / 256), 256, 0, stream>>>(
      x, x_bf, (long long)M * H);
  // 2,3) W_c^T, W_p^T (f32 -> bf16)
  transpose_f32_bf16_kernel<<<dim3(3 * Ha / 32, H / 32), tb, 0, stream>>>(W_c, Wc_t, H, 3 * Ha);
  transpose_f32_bf16_kernel<<<dim3(P / 32, Ha / 32), tb, 0, stream>>>(W_p, Wp_t, Ha, P);
  // 4) qkv = x @ W_c + b_c   (bf16 out, ld 3072)  [256^2 v2]
  gemm256v2<EPI_BF16_BIAS><<<dim3(3 * Ha / 256, M / 256, 1), 512, 0, stream>>>(
      x_bf, 0, H, Wc_t, 0, H, qkv, 0, 3 * Ha, b_c, nullptr, 0, 0.f, H);
  // 5) scores = (Q @ K^T) * rsqrt(1024) + score_weights   (fp32)  [256^2 v2]
  gemm256v2<EPI_F32_SCALE_ADD><<<dim3(S / 256, S / 256, Bb), 512, 0, stream>>>(
      qkv, (long long)S * 3 * Ha, 3 * Ha,
      qkv + Ha, (long long)S * 3 * Ha, 3 * Ha,
      scores, (long long)S * S, S, nullptr, sw, (long long)S * S, 0.03125f, Ha);
  // 6) softmax -> bf16 probs
  softmax_rows<<<Bb * S, 256, 0, stream>>>(scores, probs);
  // 7) V^T per batch
  transpose_bf16_kernel<<<dim3(Ha / 32, S / 32, Bb), tb, 0, stream>>>(
      qkv + 2 * Ha, (long long)S * 3 * Ha, 3 * Ha, Vt, (long long)Ha * S, S);
  // 8) ctx = probs @ V   (bf16 out)  [128^2 proven]
  gemm_nt<EPI_BF16_BIAS><<<dim3(Ha / 128, S / 128, Bb), 256, 0, stream>>>(
      probs, (long long)S * S, S, Vt, (long long)Ha * S, S,
      ctx, (long long)S * Ha, Ha, nullptr, nullptr, 0, 0.f, S);
  // 9) out = ctx @ W_p + b_p   (fp32 out)  [128^2 proven]
  gemm_nt<EPI_F32_BIAS><<<dim3(P / 128, M / 128, 1), 256, 0, stream>>>(
      ctx, 0, Ha, Wp_t, 0, Ha, out, 0, P, b_p, nullptr, 0, 0.f, Ha);
}

// Round 5
// 253.276 us; speedup vs baseline: 1.2747x; 1.1755x over previous
//
#include <hip/hip_runtime.h>
#include <hip/hip_bf16.h>
#include <cstdint>

typedef __attribute__((ext_vector_type(8))) short v8s;   // 8 x bf16 (4 VGPR) MFMA frag
typedef __attribute__((ext_vector_type(4))) float v4f;   // MFMA accum

__device__ __forceinline__ unsigned short f32_to_bf16(float f) {
  unsigned int u = __builtin_bit_cast(unsigned int, f);
  u += 0x7fffu + ((u >> 16) & 1u);           // RNE
  return (unsigned short)(u >> 16);
}

__device__ __forceinline__ void gload_lds16(const void* g, void* l) {
  __builtin_amdgcn_global_load_lds((const __attribute__((address_space(1))) void*)g,
                                   (__attribute__((address_space(3))) void*)l, 16, 0, 0);
}

enum { EPI_BF16_BIAS = 0, EPI_F32_BIAS = 1, EPI_F32_SCALE_ADD = 2 };

// ---------------------------------------------------------------------------
// 128x128 NT GEMM, 2-phase double-buffered (T3 minimum recipe):
//   prologue: STAGE(buf0, t0); barrier
//   loop t:   STAGE(buf^1, t+1) issued FIRST; ds_read+MFMA from buf;
//             __syncthreads (vmcnt(0)+lgkmcnt(0)+barrier) — next tile landed.
// LDS 64 KiB -> 2 blocks/CU. Source-swizzled staging (cb ^= row&7): frag
// ds_read_b128 conflict-free (validated round 1, SQ_LDS_BANK_CONFLICT=0).
// Optional Vt fusion (QKV only): blocks with tileN>=2048 write V^T[b][d][s]
// instead of qkv (packed ushort4 along s).
// ---------------------------------------------------------------------------
template <int MODE>
__global__ __launch_bounds__(256)
void gemm_nt(const unsigned short* __restrict__ A, long long strideA, int lda,
             const unsigned short* __restrict__ B, long long strideB, int ldb,
             void* __restrict__ Cout, long long strideC, int ldc,
             const float* __restrict__ bias,
             const float* __restrict__ addmat, long long strideAdd,
             float scale, int K,
             unsigned short* __restrict__ VtOut)   // nullable; QKV fusion only
{
  __shared__ __attribute__((aligned(16))) short smA[2][128 * 64];  // 2 x 16 KiB
  __shared__ __attribute__((aligned(16))) short smB[2][128 * 64];

  const int tid  = threadIdx.x;
  const int lane = tid & 63;
  const int wave = tid >> 6;
  const int wm = wave >> 1, wn = wave & 1;
  const int bz = blockIdx.z;
  const int tileM = blockIdx.y * 128, tileN = blockIdx.x * 128;

  const unsigned short* Ag = A + (long long)bz * strideA + (long long)tileM * lda;
  const unsigned short* Bg = B + (long long)bz * strideB + (long long)tileN * ldb;

  const int l8    = lane >> 3;
  const int srcCb = (lane & 7) ^ l8;

  v4f acc[4][4] = {};
  const int nt = K >> 6;

#define STAGE128(buf, t) do { \
    _Pragma("unroll") \
    for (int i_ = 0; i_ < 4; ++i_) { \
      const int c_   = wave * 4 + i_; \
      const int row_ = c_ * 8 + l8; \
      gload_lds16(Ag + (long long)row_ * lda + (long long)(t) * 64 + srcCb * 8, \
                  &smA[buf][c_ * 512]); \
      gload_lds16(Bg + (long long)row_ * ldb + (long long)(t) * 64 + srcCb * 8, \
                  &smB[buf][c_ * 512]); \
    } \
  } while (0)

  // prologue
  STAGE128(0, 0);
  __syncthreads();

  for (int t = 0; t < nt; ++t) {
    const int cur = t & 1;
    if (t + 1 < nt) STAGE128(cur ^ 1, t + 1);   // issue next-tile loads first
    #pragma unroll
    for (int kk = 0; kk < 2; ++kk) {
      v8s af[4], bf[4];
      #pragma unroll
      for (int f = 0; f < 4; ++f) {
        const int rA = wm * 64 + f * 16 + (lane & 15);
        const int cA = (kk * 4 + (lane >> 4)) ^ (rA & 7);
        af[f] = *(const v8s*)&smA[cur][rA * 64 + cA * 8];
        const int rB = wn * 64 + f * 16 + (lane & 15);
        const int cB = (kk * 4 + (lane >> 4)) ^ (rB & 7);
        bf[f] = *(const v8s*)&smB[cur][rB * 64 + cB * 8];
      }
      #pragma unroll
      for (int fm = 0; fm < 4; ++fm)
        #pragma unroll
        for (int fn = 0; fn < 4; ++fn)
          acc[fm][fn] = __builtin_amdgcn_mfma_f32_16x16x32_bf16(af[fm], bf[fn], acc[fm][fn], 0, 0, 0);
    }
    __syncthreads();   // vmcnt(0)+lgkmcnt(0)+barrier: next tile landed, WAR safe
  }
#undef STAGE128

  // ---- epilogue: C/D layout col=lane&15, row=(lane>>4)*4+reg ----
  const int row0 = tileM + wm * 64 + (lane >> 4) * 4;
  const int col0 = tileN + wn * 64 + (lane & 15);
  const bool vtActive = (MODE == EPI_BF16_BIAS) && (VtOut != nullptr) && (tileN >= 2048);

  #pragma unroll
  for (int fm = 0; fm < 4; ++fm) {
    #pragma unroll
    for (int fn = 0; fn < 4; ++fn) {
      const int col = col0 + fn * 16;
      if (vtActive) {
        // V^T write: d = col-2048, batch = row>>11, s = row&2047 (4 consecutive)
        const int rowb = row0 + fm * 16;
        const int d = col - 2048;
        const int b = rowb >> 11;
        const int s0 = rowb & 2047;
        const float bb = bias[col];
        ushort4 w;
        w.x = f32_to_bf16(acc[fm][fn][0] + bb);
        w.y = f32_to_bf16(acc[fm][fn][1] + bb);
        w.z = f32_to_bf16(acc[fm][fn][2] + bb);
        w.w = f32_to_bf16(acc[fm][fn][3] + bb);
        *(ushort4*)&VtOut[((long long)b * 1024 + d) * 2048 + s0] = w;
      } else {
        #pragma unroll
        for (int r = 0; r < 4; ++r) {
          const int row = row0 + fm * 16 + r;
          const float v = acc[fm][fn][r];
          if (MODE == EPI_F32_SCALE_ADD) {
            float* C = (float*)Cout + (long long)bz * strideC;
            const float* Wt = addmat + (long long)bz * strideAdd;
            C[(long long)row * ldc + col] = v * scale + Wt[(long long)row * ldc + col];
          } else if (MODE == EPI_F32_BIAS) {
            float* C = (float*)Cout + (long long)bz * strideC;
            C[(long long)row * ldc + col] = v + bias[col];
          } else {
            unsigned short* C = (unsigned short*)Cout + (long long)bz * strideC;
            const float b = bias ? bias[col] : 0.0f;
            C[(long long)row * ldc + col] = f32_to_bf16(v + b);
          }
        }
      }
    }
  }
}

// ---------------------------------------------------------------------------
__global__ __launch_bounds__(256)
void cvt_f32_bf16_kernel(const float* __restrict__ in, unsigned short* __restrict__ out,
                         long long n)
{
  const long long i = ((long long)blockIdx.x * 256 + threadIdx.x) * 4;
  if (i >= n) return;
  const float4 v = *(const float4*)(in + i);
  typedef __attribute__((ext_vector_type(4))) unsigned short v4us;
  v4us o;
  o.x = f32_to_bf16(v.x); o.y = f32_to_bf16(v.y);
  o.z = f32_to_bf16(v.z); o.w = f32_to_bf16(v.w);
  *(v4us*)(out + i) = o;
}

__global__ __launch_bounds__(256)
void transpose_f32_bf16_kernel(const float* __restrict__ in, unsigned short* __restrict__ out,
                               int R, int C)   // in [R][C] f32 -> out [C][R] bf16
{
  __shared__ float t[32][33];
  const int c0 = blockIdx.x * 32, r0 = blockIdx.y * 32;
  const int tx = threadIdx.x, ty = threadIdx.y;
  for (int i = ty; i < 32; i += 8)
    t[i][tx] = in[(long long)(r0 + i) * C + (c0 + tx)];
  __syncthreads();
  for (int i = ty; i < 32; i += 8)
    out[(long long)(c0 + i) * R + (r0 + tx)] = f32_to_bf16(t[tx][i]);
}

// one block (256 thr) per row of 2048 fp32 scores -> bf16 probs
__global__ __launch_bounds__(256)
void softmax_rows(const float* __restrict__ scores, unsigned short* __restrict__ probs)
{
  const long long row = blockIdx.x;
  const float* src = scores + row * 2048;
  unsigned short* dst = probs + row * 2048;
  const int t = threadIdx.x;
  float v[8];
  const float4 a = *(const float4*)(src + t * 8);
  const float4 b = *(const float4*)(src + t * 8 + 4);
  v[0]=a.x; v[1]=a.y; v[2]=a.z; v[3]=a.w; v[4]=b.x; v[5]=b.y; v[6]=b.z; v[7]=b.w;

  float m = v[0];
  #pragma unroll
  for (int j = 1; j < 8; ++j) m = fmaxf(m, v[j]);
  for (int o = 32; o; o >>= 1) m = fmaxf(m, __shfl_xor(m, o));
  __shared__ float redm[4], reds[4];
  if ((t & 63) == 0) redm[t >> 6] = m;
  __syncthreads();
  m = fmaxf(fmaxf(redm[0], redm[1]), fmaxf(redm[2], redm[3]));

  float s = 0.f;
  #pragma unroll
  for (int j = 0; j < 8; ++j) { v[j] = __expf(v[j] - m); s += v[j]; }
  for (int o = 32; o; o >>= 1) s += __shfl_xor(s, o);
  if ((t & 63) == 0) reds[t >> 6] = s;
  __syncthreads();
  s = reds[0] + reds[1] + reds[2] + reds[3];
  const float inv = 1.0f / s;

  v8s o8;
  #pragma unroll
  for (int j = 0; j < 8; ++j) o8[j] = (short)f32_to_bf16(v[j] * inv);
  *(v8s*)(dst + t * 8) = o8;
}

// ---------------------------------------------------------------------------
extern "C" void kernel_launch(void* const* d_in, const int* in_sizes, int n_in,
                              void* d_out, int out_size, void* d_ws, size_t ws_size,
                              hipStream_t stream) {
  (void)in_sizes; (void)n_in; (void)out_size; (void)ws_size;
  const float* x   = (const float*)d_in[0];
  const float* sw  = (const float*)d_in[1];
  const float* W_c = (const float*)d_in[2];
  const float* b_c = (const float*)d_in[3];
  const float* W_p = (const float*)d_in[4];
  const float* b_p = (const float*)d_in[5];
  float* out = (float*)d_out;

  const int Bb = 4, S = 2048, H = 1024, Ha = 1024, P = 1024;
  const int M = Bb * S;                              // 8192
  char* ws = (char*)d_ws;
  const long long MB = 1024LL * 1024LL;
  // ws layout (168 MB), time-sliced overlap in [0,64MB):
  //   x_bf [0,16) steps 1-4 | scores [0,64) steps 5-6 | ctx [0,16) steps 7-8
  float*          scores = (float*)(ws + 0);
  unsigned short* x_bf   = (unsigned short*)(ws + 0);
  unsigned short* ctx    = (unsigned short*)(ws + 0);
  unsigned short* probs  = (unsigned short*)(ws + 64 * MB);   // 32 MB
  unsigned short* qkv    = (unsigned short*)(ws + 96 * MB);   // 48 MB [8192][3072] (V third unused)
  unsigned short* Vt     = (unsigned short*)(ws + 144 * MB);  // 16 MB [4][1024][2048]
  unsigned short* Wc_t   = (unsigned short*)(ws + 160 * MB);  // 6 MB  [3072][1024]
  unsigned short* Wp_t   = (unsigned short*)(ws + 166 * MB);  // 2 MB  [1024][1024]

  const dim3 tb(32, 8);

  // 1) x -> bf16
  cvt_f32_bf16_kernel<<<(unsigned)((long long)M * H / 4 / 256), 256, 0, stream>>>(
      x, x_bf, (long long)M * H);
  // 2,3) W_c^T, W_p^T (f32 -> bf16)
  transpose_f32_bf16_kernel<<<dim3(3 * Ha / 32, H / 32), tb, 0, stream>>>(W_c, Wc_t, H, 3 * Ha);
  transpose_f32_bf16_kernel<<<dim3(P / 32, Ha / 32), tb, 0, stream>>>(W_p, Wp_t, Ha, P);
  // 4) qkv = x @ W_c + b_c; Q,K -> qkv (bf16), V -> Vt (transposed, fused)
  gemm_nt<EPI_BF16_BIAS><<<dim3(3 * Ha / 128, M / 128, 1), 256, 0, stream>>>(
      x_bf, 0, H, Wc_t, 0, H, qkv, 0, 3 * Ha, b_c, nullptr, 0, 0.f, H, Vt);
  // 5) scores = (Q @ K^T) * rsqrt(1024) + score_weights   (fp32)
  gemm_nt<EPI_F32_SCALE_ADD><<<dim3(S / 128, S / 128, Bb), 256, 0, stream>>>(
      qkv, (long long)S * 3 * Ha, 3 * Ha,
      qkv + Ha, (long long)S * 3 * Ha, 3 * Ha,
      scores, (long long)S * S, S, nullptr, sw, (long long)S * S, 0.03125f, Ha, nullptr);
  // 6) softmax -> bf16 probs
  softmax_rows<<<Bb * S, 256, 0, stream>>>(scores, probs);
  // 7) ctx = probs @ V   (bf16 out)
  gemm_nt<EPI_BF16_BIAS><<<dim3(Ha / 128, S / 128, Bb), 256, 0, stream>>>(
      probs, (long long)S * S, S, Vt, (long long)Ha * S, S,
      ctx, (long long)S * Ha, Ha, nullptr, nullptr, 0, 0.f, S, nullptr);
  // 8) out = ctx @ W_p + b_p   (fp32 out)
  gemm_nt<EPI_F32_BIAS><<<dim3(P / 128, M / 128, 1), 256, 0, stream>>>(
      ctx, 0, Ha, Wp_t, 0, Ha, out, 0, P, b_p, nullptr, 0, 0.f, Ha, nullptr);
}